// Round 5
// baseline (970.837 us; speedup 1.0000x reference)
//
#include <hip/hip_runtime.h>
#include <hip/hip_bf16.h>
#include <cstdint>
#include <cstddef>

// GCN: 6 layers (128->64, then 5x 64->64), gcn_norm with self-loops,
// sum+max pooling over 64 graphs, 3-layer MLP head.
// Norm factored: h[v] = relu(b + dinv[v]*(t'[v] + sum_e t'[src_e])),
//   t'[r] = dinv[r]*(h_prev[r]@W)  stored bf16 (128B gather rows).
// FUSION: the next layer's transform (h@W_next) runs in the agg epilogue
// (W_next cols in VGPRs, h broadcast via per-wave LDS row), so only ONE
// real GEMM remains (layer 0, K=128). CSR built XCD-sliced.

#define FEAT 64

static __device__ inline unsigned short f2bf(float f) {
  unsigned u = __float_as_uint(f);
  unsigned r = (u + 0x7FFF + ((u >> 16) & 1)) >> 16;  // round-to-nearest-even
  return (unsigned short)r;
}
static __device__ inline float bf2f(unsigned short u) {
  return __uint_as_float(((unsigned)u) << 16);
}

// ---------------- setup kernels ----------------

__global__ __launch_bounds__(256) void init_kernel(int* deg, int* cursor,
    float* gsum, unsigned int* gmax, int n) {
  int i = blockIdx.x * 256 + threadIdx.x;
  if (i < n) { deg[i] = 0; cursor[i] = 0; }
  if (i < 64 * FEAT) { gsum[i] = 0.f; gmax[i] = 0xFF800000u; }  // -inf bits
}

// XCD-sliced histogram: slice s = blockIdx%8 owns dst in [s*n/8,(s+1)*n/8).
__global__ __launch_bounds__(256) void hist_kernel(const int* __restrict__ dst,
    int* __restrict__ deg, int e, int n) {
  const int slice = blockIdx.x & 7;
  const int lo = slice * (n >> 3);
  const int hi = lo + (n >> 3);
  const int nb = gridDim.x >> 3;
  const int bid = blockIdx.x >> 3;
  for (int i = bid * 256 + threadIdx.x; i < e; i += nb * 256) {
    int d = dst[i];
    if (d >= lo && d < hi) atomicAdd(&deg[d], 1);
  }
}

__global__ __launch_bounds__(256) void dinv_kernel(const int* __restrict__ deg,
    float* __restrict__ dinv, int n) {
  int i = blockIdx.x * 256 + threadIdx.x;
  if (i < n) dinv[i] = rsqrtf((float)(deg[i] + 1));  // +1 self-loop; always >=1
}

__global__ __launch_bounds__(256) void scan1_kernel(const int* __restrict__ deg,
    int* __restrict__ offs, int* __restrict__ bsums, int n) {
  __shared__ int buf[256];
  int t = threadIdx.x;
  int i = blockIdx.x * 256 + t;
  int v = (i < n) ? deg[i] : 0;
  buf[t] = v;
  __syncthreads();
  for (int off = 1; off < 256; off <<= 1) {
    int add = (t >= off) ? buf[t - off] : 0;
    __syncthreads();
    buf[t] += add;
    __syncthreads();
  }
  if (i < n) offs[i] = buf[t] - v;           // exclusive within block
  if (t == 255) bsums[blockIdx.x] = buf[255];
}

__global__ __launch_bounds__(512) void scan2_kernel(int* bs, int nb) {
  __shared__ int buf[512];
  int t = threadIdx.x;
  int v = (t < nb) ? bs[t] : 0;
  buf[t] = v;
  __syncthreads();
  for (int off = 1; off < 512; off <<= 1) {
    int add = (t >= off) ? buf[t - off] : 0;
    __syncthreads();
    buf[t] += add;
    __syncthreads();
  }
  if (t < nb) bs[t] = buf[t] - v;            // exclusive block offsets
}

__global__ __launch_bounds__(256) void scan3_kernel(int* __restrict__ offs,
    const int* __restrict__ bs, int n) {
  int i = blockIdx.x * 256 + threadIdx.x;
  if (i < n) offs[i] += bs[blockIdx.x];
}

// XCD-sliced CSR fill: slice's cursor + CSR region stay L2-local so 4B
// scatters coalesce before writeback.
__global__ __launch_bounds__(256) void fill_kernel(const int* __restrict__ src,
    const int* __restrict__ dst, const int* __restrict__ offs,
    int* __restrict__ cursor, int* __restrict__ csr_src, int e, int n) {
  const int slice = blockIdx.x & 7;
  const int lo = slice * (n >> 3);
  const int hi = lo + (n >> 3);
  const int nb = gridDim.x >> 3;
  const int bid = blockIdx.x >> 3;
  for (int i = bid * 256 + threadIdx.x; i < e; i += nb * 256) {
    int d = dst[i];
    if (d >= lo && d < hi) {
      int pos = offs[d] + atomicAdd(&cursor[d], 1);
      csr_src[pos] = src[i];
    }
  }
}

// ---------------- GEMM0: tg[N,64](bf16) = dinv[r] * (x[N,128] @ W[128,64]) --
template <int K>
__global__ __launch_bounds__(256, 2) void gemm_kernel(
    const float* __restrict__ in, const float* __restrict__ W,
    const float* __restrict__ dinv, unsigned short* __restrict__ tg, int n) {
  __shared__ float in_lds[64 * K];
  const int lane = threadIdx.x & 63;
  const int wid = threadIdx.x >> 6;

  float wreg[K];
#pragma unroll
  for (int k = 0; k < K; ++k) wreg[k] = W[k * 64 + lane];

  const int ntiles = n >> 6;
  for (int tile = blockIdx.x; tile < ntiles; tile += gridDim.x) {
    const float* tin = in + (size_t)tile * 64 * K;
    __syncthreads();  // previous tile's compute done before overwrite
#pragma unroll
    for (int i = threadIdx.x; i < 16 * K; i += 256)
      *(float4*)&in_lds[i * 4] = *(const float4*)&tin[i * 4];
    __syncthreads();

    unsigned short* tout = tg + (size_t)tile * 64 * 64;
    const float* dvp = dinv + tile * 64;
#pragma unroll
    for (int g = 0; g < 4; ++g) {
      const int r0 = wid * 16 + g * 4;
      float a0 = 0.f, a1 = 0.f, a2 = 0.f, a3 = 0.f;
#pragma unroll
      for (int k = 0; k < K; k += 4) {
        float4 x0 = *(const float4*)&in_lds[(r0 + 0) * K + k];
        float4 x1 = *(const float4*)&in_lds[(r0 + 1) * K + k];
        float4 x2 = *(const float4*)&in_lds[(r0 + 2) * K + k];
        float4 x3 = *(const float4*)&in_lds[(r0 + 3) * K + k];
        a0 = fmaf(x0.x, wreg[k + 0], a0); a0 = fmaf(x0.y, wreg[k + 1], a0);
        a0 = fmaf(x0.z, wreg[k + 2], a0); a0 = fmaf(x0.w, wreg[k + 3], a0);
        a1 = fmaf(x1.x, wreg[k + 0], a1); a1 = fmaf(x1.y, wreg[k + 1], a1);
        a1 = fmaf(x1.z, wreg[k + 2], a1); a1 = fmaf(x1.w, wreg[k + 3], a1);
        a2 = fmaf(x2.x, wreg[k + 0], a2); a2 = fmaf(x2.y, wreg[k + 1], a2);
        a2 = fmaf(x2.z, wreg[k + 2], a2); a2 = fmaf(x2.w, wreg[k + 3], a2);
        a3 = fmaf(x3.x, wreg[k + 0], a3); a3 = fmaf(x3.y, wreg[k + 1], a3);
        a3 = fmaf(x3.z, wreg[k + 2], a3); a3 = fmaf(x3.w, wreg[k + 3], a3);
      }
      tout[(r0 + 0) * 64 + lane] = f2bf(a0 * dvp[r0 + 0]);
      tout[(r0 + 1) * 64 + lane] = f2bf(a1 * dvp[r0 + 1]);
      tout[(r0 + 2) * 64 + lane] = f2bf(a2 * dvp[r0 + 2]);
      tout[(r0 + 3) * 64 + lane] = f2bf(a3 * dvp[r0 + 3]);
    }
  }
}

// ---------------- fused AGG+transform (layers 0..4) ----------------
// One wave per node; lane = feature. Gather bf16 rows, h = relu(b+dinv*acc),
// then t'_next[lane] = dinv * sum_f h[f]*Wn[f][lane] via per-wave LDS row
// broadcast (DS pipe is in-order per wave -> no __syncthreads needed).
__global__ __launch_bounds__(256) void agg_mid_kernel(
    const unsigned short* __restrict__ tg_in, const int* __restrict__ csr_src,
    const int* __restrict__ offs, const int* __restrict__ cnt,
    const float* __restrict__ dinv, const float* __restrict__ bias,
    const float* __restrict__ Wn, unsigned short* __restrict__ tg_out, int n) {
  __shared__ float hrow[4][64];
  const int lane = threadIdx.x & 63;
  const int wid = threadIdx.x >> 6;

  float wn[64];
#pragma unroll
  for (int f = 0; f < 64; ++f) wn[f] = Wn[f * 64 + lane];

  int v = (blockIdx.x * 256 + threadIdx.x) >> 6;
  if (v >= n) return;

  float acc = bf2f(tg_in[(size_t)v * 64 + lane]);  // self term
  int j = offs[v];
  int end = j + cnt[v];
  for (; j + 7 < end; j += 8) {
    int s0 = csr_src[j + 0], s1 = csr_src[j + 1];
    int s2 = csr_src[j + 2], s3 = csr_src[j + 3];
    int s4 = csr_src[j + 4], s5 = csr_src[j + 5];
    int s6 = csr_src[j + 6], s7 = csr_src[j + 7];
    float t0 = bf2f(tg_in[(size_t)s0 * 64 + lane]);
    float t1 = bf2f(tg_in[(size_t)s1 * 64 + lane]);
    float t2 = bf2f(tg_in[(size_t)s2 * 64 + lane]);
    float t3 = bf2f(tg_in[(size_t)s3 * 64 + lane]);
    float t4 = bf2f(tg_in[(size_t)s4 * 64 + lane]);
    float t5 = bf2f(tg_in[(size_t)s5 * 64 + lane]);
    float t6 = bf2f(tg_in[(size_t)s6 * 64 + lane]);
    float t7 = bf2f(tg_in[(size_t)s7 * 64 + lane]);
    acc += ((t0 + t1) + (t2 + t3)) + ((t4 + t5) + (t6 + t7));
  }
  for (; j < end; ++j)
    acc += bf2f(tg_in[(size_t)csr_src[j] * 64 + lane]);

  float h = fmaxf(fmaf(dinv[v], acc, bias[lane]), 0.f);  // relu (layers 0..4)

  hrow[wid][lane] = h;  // wave-private LDS row; DS pipe in-order per wave
  float tval = 0.f;
#pragma unroll
  for (int f = 0; f < 64; f += 4) {
    float4 h4 = *(const float4*)&hrow[wid][f];  // uniform broadcast b128
    tval = fmaf(h4.x, wn[f + 0], tval);
    tval = fmaf(h4.y, wn[f + 1], tval);
    tval = fmaf(h4.z, wn[f + 2], tval);
    tval = fmaf(h4.w, wn[f + 3], tval);
  }
  tg_out[(size_t)v * 64 + lane] = f2bf(dinv[v] * tval);
}

// ---------------- last AGG (layer 5): no relu, no transform, f32 out ------
__global__ __launch_bounds__(256) void agg_last_kernel(
    const unsigned short* __restrict__ tg_in, const int* __restrict__ csr_src,
    const int* __restrict__ offs, const int* __restrict__ cnt,
    const float* __restrict__ dinv, const float* __restrict__ bias,
    float* __restrict__ h, int n) {
  int v = (blockIdx.x * 256 + threadIdx.x) >> 6;
  int lane = threadIdx.x & 63;
  if (v >= n) return;
  float acc = bf2f(tg_in[(size_t)v * 64 + lane]);
  int j = offs[v];
  int end = j + cnt[v];
  for (; j + 7 < end; j += 8) {
    int s0 = csr_src[j + 0], s1 = csr_src[j + 1];
    int s2 = csr_src[j + 2], s3 = csr_src[j + 3];
    int s4 = csr_src[j + 4], s5 = csr_src[j + 5];
    int s6 = csr_src[j + 6], s7 = csr_src[j + 7];
    float t0 = bf2f(tg_in[(size_t)s0 * 64 + lane]);
    float t1 = bf2f(tg_in[(size_t)s1 * 64 + lane]);
    float t2 = bf2f(tg_in[(size_t)s2 * 64 + lane]);
    float t3 = bf2f(tg_in[(size_t)s3 * 64 + lane]);
    float t4 = bf2f(tg_in[(size_t)s4 * 64 + lane]);
    float t5 = bf2f(tg_in[(size_t)s5 * 64 + lane]);
    float t6 = bf2f(tg_in[(size_t)s6 * 64 + lane]);
    float t7 = bf2f(tg_in[(size_t)s7 * 64 + lane]);
    acc += ((t0 + t1) + (t2 + t3)) + ((t4 + t5) + (t6 + t7));
  }
  for (; j < end; ++j)
    acc += bf2f(tg_in[(size_t)csr_src[j] * 64 + lane]);
  h[(size_t)v * 64 + lane] = fmaf(dinv[v], acc, bias[lane]);  // no relu
}

// ---------------- pooling: per-graph sum + max ----------------

__device__ inline void atomic_max_float(float* addr, float val) {
  if (val >= 0.f)
    atomicMax((int*)addr, __float_as_int(val));
  else
    atomicMin((unsigned int*)addr, (unsigned int)__float_as_int(val));
}

#define POOL_CHUNK 128

__global__ __launch_bounds__(256) void pool_kernel(const float* __restrict__ h,
    const int* __restrict__ batch, float* __restrict__ gsum,
    float* __restrict__ gmax, int n) {
  int wave = (blockIdx.x * 256 + threadIdx.x) >> 6;
  int lane = threadIdx.x & 63;
  int start = wave * POOL_CHUNK;
  if (start >= n) return;
  int end = min(start + POOL_CHUNK, n);
  float s = 0.f, m = -INFINITY;
  int cur = batch[start];
  for (int v = start; v < end; ++v) {
    int g = batch[v];
    if (g != cur) {
      atomicAdd(&gsum[cur * 64 + lane], s);
      atomic_max_float(&gmax[cur * 64 + lane], m);
      s = 0.f; m = -INFINITY; cur = g;
    }
    float x = h[(size_t)v * 64 + lane];
    s += x;
    m = fmaxf(m, x);
  }
  atomicAdd(&gsum[cur * 64 + lane], s);
  atomic_max_float(&gmax[cur * 64 + lane], m);
}

// ---------------- MLP head (single block) ----------------

__global__ __launch_bounds__(256) void mlp_kernel(const float* __restrict__ gsum,
    const float* __restrict__ gmax, const float* __restrict__ w1,
    const float* __restrict__ b1, const float* __restrict__ w2,
    const float* __restrict__ b2, const float* __restrict__ w3,
    const float* __restrict__ b3, float* __restrict__ out) {
  __shared__ float smem[64 * 128 + 64 * 64];  // 48KB: gg then z1; z2 overlays gg
  float* gg = smem;
  float* z1 = smem + 64 * 128;
  int t = threadIdx.x;
  for (int i = t; i < 64 * 128; i += 256) {
    int g = i >> 7, f = i & 127;
    gg[i] = (f < 64) ? gsum[g * 64 + f] : gmax[g * 64 + (f - 64)];
  }
  __syncthreads();
  for (int i = t; i < 64 * 64; i += 256) {
    int g = i >> 6, j = i & 63;
    float acc = b1[j];
    for (int f = 0; f < 128; ++f) acc = fmaf(gg[(g << 7) + f], w1[f * 64 + j], acc);
    z1[i] = fmaxf(acc, 0.f);
  }
  __syncthreads();
  float* z2 = smem;  // gg region is dead now
  for (int i = t; i < 64 * 64; i += 256) {
    int g = i >> 6, j = i & 63;
    float acc = b2[j];
    for (int f = 0; f < 64; ++f) acc = fmaf(z1[(g << 6) + f], w2[f * 64 + j], acc);
    z2[i] = fmaxf(acc, 0.f);
  }
  __syncthreads();
  if (t < 64) {
    float acc = b3[0];
    for (int j = 0; j < 64; ++j) acc = fmaf(z2[(t << 6) + j], w3[j], acc);
    out[t] = acc;
  }
}

// ---------------- launch ----------------

extern "C" void kernel_launch(void* const* d_in, const int* in_sizes, int n_in,
                              void* d_out, int out_size, void* d_ws, size_t ws_size,
                              hipStream_t stream) {
  const float* x      = (const float*)d_in[0];
  const int*   eidx   = (const int*)d_in[1];
  const int*   batch  = (const int*)d_in[2];
  const float* W_in   = (const float*)d_in[3];
  const float* b_in   = (const float*)d_in[4];
  const float* W_hid  = (const float*)d_in[5];
  const float* b_hid  = (const float*)d_in[6];
  const float* lin1_w = (const float*)d_in[7];
  const float* lin1_b = (const float*)d_in[8];
  const float* lin2_w = (const float*)d_in[9];
  const float* lin2_b = (const float*)d_in[10];
  const float* lin3_w = (const float*)d_in[11];
  const float* lin3_b = (const float*)d_in[12];
  float* out = (float*)d_out;

  const int N = in_sizes[2];            // 80000
  const int E = in_sizes[1] / 2;        // 1280000
  const int CIN = in_sizes[0] / N;      // 128
  const int n_hid = in_sizes[5] / (64 * 64);  // 5

  const int* src = eidx;
  const int* dst = eidx + E;

  // workspace layout (256B-aligned slabs)
  char* ws = (char*)d_ws;
  size_t off = 0;
  auto alloc = [&](size_t bytes) {
    size_t o = off;
    off = (off + bytes + 255) & ~(size_t)255;
    return o;
  };
  int*            deg     = (int*)(ws + alloc((size_t)N * 4));
  int*            cursor  = (int*)(ws + alloc((size_t)N * 4));
  float*          dinv    = (float*)(ws + alloc((size_t)N * 4));
  int*            offs    = (int*)(ws + alloc((size_t)N * 4));
  int*            bsums   = (int*)(ws + alloc(1024 * 4));
  int*            csr_src = (int*)(ws + alloc((size_t)E * 4));
  unsigned short* tg_a    = (unsigned short*)(ws + alloc((size_t)N * 64 * 2));
  unsigned short* tg_b    = (unsigned short*)(ws + alloc((size_t)N * 64 * 2));
  float*          hbuf    = (float*)(ws + alloc((size_t)N * 64 * 4));
  float*          gsum    = (float*)(ws + alloc(64 * 64 * 4));
  float*          gmax    = (float*)(ws + alloc(64 * 64 * 4));
  (void)ws_size; (void)n_in; (void)out_size; (void)CIN;

  const int nbN = (N + 255) / 256;   // 313

  init_kernel<<<nbN, 256, 0, stream>>>(deg, cursor, gsum, (unsigned int*)gmax, N);
  hist_kernel<<<1024, 256, 0, stream>>>(dst, deg, E, N);
  dinv_kernel<<<nbN, 256, 0, stream>>>(deg, dinv, N);
  scan1_kernel<<<nbN, 256, 0, stream>>>(deg, offs, bsums, N);
  scan2_kernel<<<1, 512, 0, stream>>>(bsums, nbN);
  scan3_kernel<<<nbN, 256, 0, stream>>>(offs, bsums, N);
  fill_kernel<<<1024, 256, 0, stream>>>(src, dst, offs, cursor, csr_src, E, N);

  const int ntiles = N >> 6;                    // 1250 (N % 64 == 0)
  const int agg_blocks = (N * 64 + 255) / 256;  // one wave per node

  // layer 0 GEMM: t'_0 = dinv * (x @ W_in), bf16
  gemm_kernel<128><<<ntiles, 256, 0, stream>>>(x, W_in, dinv, tg_a, N);

  // fused conv layers: agg(t'_k) -> h_k -> t'_{k+1} = dinv*(h_k @ W_hid[k])
  // k=0 uses bias b_in; k=i (i>=1) uses b_hid[i-1]. All have relu.
  unsigned short* cur = tg_a;
  unsigned short* nxt = tg_b;
  for (int k = 0; k < n_hid; ++k) {   // 5 fused layers
    const float* bias_k = (k == 0) ? b_in : (b_hid + (size_t)(k - 1) * 64);
    agg_mid_kernel<<<agg_blocks, 256, 0, stream>>>(
        cur, csr_src, offs, deg, dinv, bias_k,
        W_hid + (size_t)k * 64 * 64, nxt, N);
    unsigned short* t = cur; cur = nxt; nxt = t;
  }
  // last conv: gather t'_5, bias b_hid[4], NO relu, f32 h for pooling
  agg_last_kernel<<<agg_blocks, 256, 0, stream>>>(
      cur, csr_src, offs, deg, dinv, b_hid + (size_t)(n_hid - 1) * 64, hbuf, N);

  const int pool_waves = (N + POOL_CHUNK - 1) / POOL_CHUNK;
  const int pool_blocks = (pool_waves * 64 + 255) / 256;
  pool_kernel<<<pool_blocks, 256, 0, stream>>>(hbuf, batch, gsum, gmax, N);

  mlp_kernel<<<1, 256, 0, stream>>>(gsum, gmax, lin1_w, lin1_b, lin2_w, lin2_b,
                                    lin3_w, lin3_b, out);
}

// Round 7
// 689.954 us; speedup vs baseline: 1.4071x; 1.4071x over previous
//
#include <hip/hip_runtime.h>
#include <hip/hip_bf16.h>
#include <cstdint>
#include <cstddef>

// GCN: 6 layers (128->64, then 5x 64->64), gcn_norm with self-loops,
// sum+max pooling over 64 graphs, 3-layer MLP head.
// Norm factored: h[v] = relu(b + dinv[v]*(t'[v] + sum_e t'[src_e])),
//   t'[r] = dinv[r]*(h_prev[r]@W)  stored bf16 (128B gather rows).
// Transforms are MFMA GEMMs with SPLIT-BF16 (hi+lo) operands: 3 products
// ah*wh + al*wh + ah*wl recover ~f32 accuracy, so the only bf16 rounding
// left is the (round-4-validated) tg store. h stays f32 in memory.
// CSR built XCD-sliced.

#define FEAT 64

typedef __bf16 bf16_t;
typedef bf16_t bf16x8 __attribute__((ext_vector_type(8)));
typedef float f32x4 __attribute__((ext_vector_type(4)));

static __device__ inline unsigned short f2bf(float f) {
  unsigned u = __float_as_uint(f);
  unsigned r = (u + 0x7FFF + ((u >> 16) & 1)) >> 16;  // round-to-nearest-even
  return (unsigned short)r;
}
static __device__ inline float bf2f(unsigned short u) {
  return __uint_as_float(((unsigned)u) << 16);
}

// ---------------- setup kernels ----------------

__global__ __launch_bounds__(256) void init_kernel(int* deg, int* cursor,
    float* gsum, unsigned int* gmax, int n) {
  int i = blockIdx.x * 256 + threadIdx.x;
  if (i < n) { deg[i] = 0; cursor[i] = 0; }
  if (i < 64 * FEAT) { gsum[i] = 0.f; gmax[i] = 0xFF800000u; }  // -inf bits
}

// XCD-sliced histogram: slice s = blockIdx%8 owns dst in [s*n/8,(s+1)*n/8).
__global__ __launch_bounds__(256) void hist_kernel(const int* __restrict__ dst,
    int* __restrict__ deg, int e, int n) {
  const int slice = blockIdx.x & 7;
  const int lo = slice * (n >> 3);
  const int hi = lo + (n >> 3);
  const int nb = gridDim.x >> 3;
  const int bid = blockIdx.x >> 3;
  for (int i = bid * 256 + threadIdx.x; i < e; i += nb * 256) {
    int d = dst[i];
    if (d >= lo && d < hi) atomicAdd(&deg[d], 1);
  }
}

__global__ __launch_bounds__(256) void dinv_kernel(const int* __restrict__ deg,
    float* __restrict__ dinv, int n) {
  int i = blockIdx.x * 256 + threadIdx.x;
  if (i < n) dinv[i] = rsqrtf((float)(deg[i] + 1));  // +1 self-loop; always >=1
}

__global__ __launch_bounds__(256) void scan1_kernel(const int* __restrict__ deg,
    int* __restrict__ offs, int* __restrict__ bsums, int n) {
  __shared__ int buf[256];
  int t = threadIdx.x;
  int i = blockIdx.x * 256 + t;
  int v = (i < n) ? deg[i] : 0;
  buf[t] = v;
  __syncthreads();
  for (int off = 1; off < 256; off <<= 1) {
    int add = (t >= off) ? buf[t - off] : 0;
    __syncthreads();
    buf[t] += add;
    __syncthreads();
  }
  if (i < n) offs[i] = buf[t] - v;           // exclusive within block
  if (t == 255) bsums[blockIdx.x] = buf[255];
}

__global__ __launch_bounds__(512) void scan2_kernel(int* bs, int nb) {
  __shared__ int buf[512];
  int t = threadIdx.x;
  int v = (t < nb) ? bs[t] : 0;
  buf[t] = v;
  __syncthreads();
  for (int off = 1; off < 512; off <<= 1) {
    int add = (t >= off) ? buf[t - off] : 0;
    __syncthreads();
    buf[t] += add;
    __syncthreads();
  }
  if (t < nb) bs[t] = buf[t] - v;            // exclusive block offsets
}

__global__ __launch_bounds__(256) void scan3_kernel(int* __restrict__ offs,
    const int* __restrict__ bs, int n) {
  int i = blockIdx.x * 256 + threadIdx.x;
  if (i < n) offs[i] += bs[blockIdx.x];
}

// XCD-sliced CSR fill: slice's cursor + CSR region stay L2-local so 4B
// scatters coalesce before writeback.
__global__ __launch_bounds__(256) void fill_kernel(const int* __restrict__ src,
    const int* __restrict__ dst, const int* __restrict__ offs,
    int* __restrict__ cursor, int* __restrict__ csr_src, int e, int n) {
  const int slice = blockIdx.x & 7;
  const int lo = slice * (n >> 3);
  const int hi = lo + (n >> 3);
  const int nb = gridDim.x >> 3;
  const int bid = blockIdx.x >> 3;
  for (int i = bid * 256 + threadIdx.x; i < e; i += nb * 256) {
    int d = dst[i];
    if (d >= lo && d < hi) {
      int pos = offs[d] + atomicAdd(&cursor[d], 1);
      csr_src[pos] = src[i];
    }
  }
}

// ---------------- W fragment prep: hi/lo split bf16 ----------------
// B-frag for mfma_f32_16x16x32_bf16: lane holds B[q*32+(lane>>4)*8+j][t*16+(lane&15)]
// wf0: W_in [128][64] -> 16 frags f = t*4+q (t<4, q<4), hi and lo planes.
// wfh: W_hid[5][64][64] -> per layer 8 frags f = t*2+q (t<4, q<2), hi/lo.
__global__ __launch_bounds__(256) void wprep_kernel(
    const float* __restrict__ W_in, const float* __restrict__ W_hid,
    unsigned short* __restrict__ wf0h, unsigned short* __restrict__ wf0l,
    unsigned short* __restrict__ wfhh, unsigned short* __restrict__ wfhl) {
  int tid = threadIdx.x;
  for (int i = tid; i < 16 * 64 * 8; i += 256) {      // 8192
    int j = i & 7, l = (i >> 3) & 63, f = i >> 9;
    int q = f & 3, t = f >> 2;
    int k = q * 32 + (l >> 4) * 8 + j, c = t * 16 + (l & 15);
    float w = W_in[k * 64 + c];
    unsigned short hi = f2bf(w);
    wf0h[i] = hi;
    wf0l[i] = f2bf(w - bf2f(hi));
  }
  for (int i = tid; i < 5 * 8 * 64 * 8; i += 256) {   // 20480
    int j = i & 7, l = (i >> 3) & 63, f = (i >> 9) & 7, m = i >> 12;
    int q = f & 1, t = f >> 1;
    int k = q * 32 + (l >> 4) * 8 + j, c = t * 16 + (l & 15);
    float w = W_hid[(m * 64 + k) * 64 + c];
    unsigned short hi = f2bf(w);
    wfhh[i] = hi;
    wfhl[i] = f2bf(w - bf2f(hi));
  }
}

// split 8 f32 into hi/lo bf16x8 fragments
static __device__ inline void split8(const float4& a, const float4& b,
                                     bf16x8& vh, bf16x8& vl) {
  union { unsigned short us[8]; bf16x8 v; } uh, ul;
  float va[8] = {a.x, a.y, a.z, a.w, b.x, b.y, b.z, b.w};
#pragma unroll
  for (int j = 0; j < 8; ++j) {
    unsigned short hi = f2bf(va[j]);
    uh.us[j] = hi;
    ul.us[j] = f2bf(va[j] - bf2f(hi));
  }
  vh = uh.v; vl = ul.v;
}

// ---------------- layer-0 transform: tg = dinv * (x[N,128] @ W_in) ------
// 2 waves per 16-row tile (each does 2 of 4 col-tiles) to bound VGPRs.
// A: x f32 -> hi/lo split in-register. 3 MFMA products per (q,t).
__global__ __launch_bounds__(256) void xform0_kernel(
    const float* __restrict__ x, const unsigned short* __restrict__ wf0h,
    const unsigned short* __restrict__ wf0l, const float* __restrict__ dinv,
    unsigned short* __restrict__ tg, int n) {
  const int lane = threadIdx.x & 63;
  const int r = lane & 15, g = lane >> 4;
  const int gw = (blockIdx.x * 256 + threadIdx.x) >> 6;
  const int th = gw & 1;          // t = th*2 + tt, tt<2
  const int tile = gw >> 1;
  if (tile >= (n >> 4)) return;

  bf16x8 wh[2][4], wl[2][4];
#pragma unroll
  for (int tt = 0; tt < 2; ++tt)
#pragma unroll
    for (int q = 0; q < 4; ++q) {
      int f = (th * 2 + tt) * 4 + q;
      wh[tt][q] = *reinterpret_cast<const bf16x8*>(&wf0h[(f * 64 + lane) * 8]);
      wl[tt][q] = *reinterpret_cast<const bf16x8*>(&wf0l[(f * 64 + lane) * 8]);
    }

  const int m0 = tile << 4;
  const float* xrow = x + (size_t)(m0 + r) * 128 + g * 8;
  f32x4 acc[2] = {{0.f, 0.f, 0.f, 0.f}, {0.f, 0.f, 0.f, 0.f}};
#pragma unroll
  for (int q = 0; q < 4; ++q) {
    float4 lo4 = *(const float4*)(xrow + q * 32);
    float4 hi4 = *(const float4*)(xrow + q * 32 + 4);
    bf16x8 ah, al;
    split8(lo4, hi4, ah, al);
#pragma unroll
    for (int tt = 0; tt < 2; ++tt) {
      acc[tt] = __builtin_amdgcn_mfma_f32_16x16x32_bf16(ah, wh[tt][q], acc[tt], 0, 0, 0);
      acc[tt] = __builtin_amdgcn_mfma_f32_16x16x32_bf16(al, wh[tt][q], acc[tt], 0, 0, 0);
      acc[tt] = __builtin_amdgcn_mfma_f32_16x16x32_bf16(ah, wl[tt][q], acc[tt], 0, 0, 0);
    }
  }
  float4 dv = *(const float4*)&dinv[m0 + g * 4];
  unsigned short* orow = tg + (size_t)m0 * 64;
#pragma unroll
  for (int tt = 0; tt < 2; ++tt) {
    int c = (th * 2 + tt) * 16 + r;
    orow[(g * 4 + 0) * 64 + c] = f2bf(acc[tt][0] * dv.x);
    orow[(g * 4 + 1) * 64 + c] = f2bf(acc[tt][1] * dv.y);
    orow[(g * 4 + 2) * 64 + c] = f2bf(acc[tt][2] * dv.z);
    orow[(g * 4 + 3) * 64 + c] = f2bf(acc[tt][3] * dv.w);
  }
}

// ---------------- hidden transform: tg = dinv * (h[N,64](f32) @ W) -----
// One wave per 16-row tile; h split hi/lo in-register; 3 products.
__global__ __launch_bounds__(256) void xform_kernel(
    const float* __restrict__ h, const unsigned short* __restrict__ wflh,
    const unsigned short* __restrict__ wfll, const float* __restrict__ dinv,
    unsigned short* __restrict__ tg, int n) {
  const int lane = threadIdx.x & 63;
  const int r = lane & 15, g = lane >> 4;
  const int tile = (blockIdx.x * 256 + threadIdx.x) >> 6;
  if (tile >= (n >> 4)) return;

  bf16x8 wh[4][2], wl[4][2];
#pragma unroll
  for (int t = 0; t < 4; ++t)
#pragma unroll
    for (int q = 0; q < 2; ++q) {
      int f = t * 2 + q;
      wh[t][q] = *reinterpret_cast<const bf16x8*>(&wflh[(f * 64 + lane) * 8]);
      wl[t][q] = *reinterpret_cast<const bf16x8*>(&wfll[(f * 64 + lane) * 8]);
    }

  const int m0 = tile << 4;
  const float* hrow = h + (size_t)(m0 + r) * 64 + g * 8;
  f32x4 acc[4] = {{0.f, 0.f, 0.f, 0.f}, {0.f, 0.f, 0.f, 0.f},
                  {0.f, 0.f, 0.f, 0.f}, {0.f, 0.f, 0.f, 0.f}};
#pragma unroll
  for (int q = 0; q < 2; ++q) {
    float4 lo4 = *(const float4*)(hrow + q * 32);
    float4 hi4 = *(const float4*)(hrow + q * 32 + 4);
    bf16x8 ah, al;
    split8(lo4, hi4, ah, al);
#pragma unroll
    for (int t = 0; t < 4; ++t) {
      acc[t] = __builtin_amdgcn_mfma_f32_16x16x32_bf16(ah, wh[t][q], acc[t], 0, 0, 0);
      acc[t] = __builtin_amdgcn_mfma_f32_16x16x32_bf16(al, wh[t][q], acc[t], 0, 0, 0);
      acc[t] = __builtin_amdgcn_mfma_f32_16x16x32_bf16(ah, wl[t][q], acc[t], 0, 0, 0);
    }
  }
  float4 dv = *(const float4*)&dinv[m0 + g * 4];
  unsigned short* orow = tg + (size_t)m0 * 64;
#pragma unroll
  for (int t = 0; t < 4; ++t) {
    orow[(g * 4 + 0) * 64 + t * 16 + r] = f2bf(acc[t][0] * dv.x);
    orow[(g * 4 + 1) * 64 + t * 16 + r] = f2bf(acc[t][1] * dv.y);
    orow[(g * 4 + 2) * 64 + t * 16 + r] = f2bf(acc[t][2] * dv.z);
    orow[(g * 4 + 3) * 64 + t * 16 + r] = f2bf(acc[t][3] * dv.w);
  }
}

// ---------------- AGG (mid): h = relu(b + dinv*(self + sum gathers)), f32
__global__ __launch_bounds__(256) void agg_mid_kernel(
    const unsigned short* __restrict__ tg_in, const int* __restrict__ csr_src,
    const int* __restrict__ offs, const int* __restrict__ cnt,
    const float* __restrict__ dinv, const float* __restrict__ bias,
    float* __restrict__ h_out, int n) {
  int v = (blockIdx.x * 256 + threadIdx.x) >> 6;
  int lane = threadIdx.x & 63;
  if (v >= n) return;
  float acc = bf2f(tg_in[(size_t)v * 64 + lane]);  // self term
  int j = offs[v];
  int end = j + cnt[v];
  for (; j + 7 < end; j += 8) {
    int s0 = csr_src[j + 0], s1 = csr_src[j + 1];
    int s2 = csr_src[j + 2], s3 = csr_src[j + 3];
    int s4 = csr_src[j + 4], s5 = csr_src[j + 5];
    int s6 = csr_src[j + 6], s7 = csr_src[j + 7];
    float t0 = bf2f(tg_in[(size_t)s0 * 64 + lane]);
    float t1 = bf2f(tg_in[(size_t)s1 * 64 + lane]);
    float t2 = bf2f(tg_in[(size_t)s2 * 64 + lane]);
    float t3 = bf2f(tg_in[(size_t)s3 * 64 + lane]);
    float t4 = bf2f(tg_in[(size_t)s4 * 64 + lane]);
    float t5 = bf2f(tg_in[(size_t)s5 * 64 + lane]);
    float t6 = bf2f(tg_in[(size_t)s6 * 64 + lane]);
    float t7 = bf2f(tg_in[(size_t)s7 * 64 + lane]);
    acc += ((t0 + t1) + (t2 + t3)) + ((t4 + t5) + (t6 + t7));
  }
  for (; j < end; ++j)
    acc += bf2f(tg_in[(size_t)csr_src[j] * 64 + lane]);
  h_out[(size_t)v * 64 + lane] = fmaxf(fmaf(dinv[v], acc, bias[lane]), 0.f);
}

// ---------------- last AGG (layer 5): no relu, f32 out for pooling ------
__global__ __launch_bounds__(256) void agg_last_kernel(
    const unsigned short* __restrict__ tg_in, const int* __restrict__ csr_src,
    const int* __restrict__ offs, const int* __restrict__ cnt,
    const float* __restrict__ dinv, const float* __restrict__ bias,
    float* __restrict__ h, int n) {
  int v = (blockIdx.x * 256 + threadIdx.x) >> 6;
  int lane = threadIdx.x & 63;
  if (v >= n) return;
  float acc = bf2f(tg_in[(size_t)v * 64 + lane]);
  int j = offs[v];
  int end = j + cnt[v];
  for (; j + 7 < end; j += 8) {
    int s0 = csr_src[j + 0], s1 = csr_src[j + 1];
    int s2 = csr_src[j + 2], s3 = csr_src[j + 3];
    int s4 = csr_src[j + 4], s5 = csr_src[j + 5];
    int s6 = csr_src[j + 6], s7 = csr_src[j + 7];
    float t0 = bf2f(tg_in[(size_t)s0 * 64 + lane]);
    float t1 = bf2f(tg_in[(size_t)s1 * 64 + lane]);
    float t2 = bf2f(tg_in[(size_t)s2 * 64 + lane]);
    float t3 = bf2f(tg_in[(size_t)s3 * 64 + lane]);
    float t4 = bf2f(tg_in[(size_t)s4 * 64 + lane]);
    float t5 = bf2f(tg_in[(size_t)s5 * 64 + lane]);
    float t6 = bf2f(tg_in[(size_t)s6 * 64 + lane]);
    float t7 = bf2f(tg_in[(size_t)s7 * 64 + lane]);
    acc += ((t0 + t1) + (t2 + t3)) + ((t4 + t5) + (t6 + t7));
  }
  for (; j < end; ++j)
    acc += bf2f(tg_in[(size_t)csr_src[j] * 64 + lane]);
  h[(size_t)v * 64 + lane] = fmaf(dinv[v], acc, bias[lane]);  // no relu
}

// ---------------- pooling: per-graph sum + max ----------------

__device__ inline void atomic_max_float(float* addr, float val) {
  if (val >= 0.f)
    atomicMax((int*)addr, __float_as_int(val));
  else
    atomicMin((unsigned int*)addr, (unsigned int)__float_as_int(val));
}

#define POOL_CHUNK 128

__global__ __launch_bounds__(256) void pool_kernel(const float* __restrict__ h,
    const int* __restrict__ batch, float* __restrict__ gsum,
    float* __restrict__ gmax, int n) {
  int wave = (blockIdx.x * 256 + threadIdx.x) >> 6;
  int lane = threadIdx.x & 63;
  int start = wave * POOL_CHUNK;
  if (start >= n) return;
  int end = min(start + POOL_CHUNK, n);
  float s = 0.f, m = -INFINITY;
  int cur = batch[start];
  for (int v = start; v < end; ++v) {
    int g = batch[v];
    if (g != cur) {
      atomicAdd(&gsum[cur * 64 + lane], s);
      atomic_max_float(&gmax[cur * 64 + lane], m);
      s = 0.f; m = -INFINITY; cur = g;
    }
    float x = h[(size_t)v * 64 + lane];
    s += x;
    m = fmaxf(m, x);
  }
  atomicAdd(&gsum[cur * 64 + lane], s);
  atomic_max_float(&gmax[cur * 64 + lane], m);
}

// ---------------- MLP head (single block) ----------------

__global__ __launch_bounds__(256) void mlp_kernel(const float* __restrict__ gsum,
    const float* __restrict__ gmax, const float* __restrict__ w1,
    const float* __restrict__ b1, const float* __restrict__ w2,
    const float* __restrict__ b2, const float* __restrict__ w3,
    const float* __restrict__ b3, float* __restrict__ out) {
  __shared__ float smem[64 * 128 + 64 * 64];  // 48KB: gg then z1; z2 overlays gg
  float* gg = smem;
  float* z1 = smem + 64 * 128;
  int t = threadIdx.x;
  for (int i = t; i < 64 * 128; i += 256) {
    int g = i >> 7, f = i & 127;
    gg[i] = (f < 64) ? gsum[g * 64 + f] : gmax[g * 64 + (f - 64)];
  }
  __syncthreads();
  for (int i = t; i < 64 * 64; i += 256) {
    int g = i >> 6, j = i & 63;
    float acc = b1[j];
    for (int f = 0; f < 128; ++f) acc = fmaf(gg[(g << 7) + f], w1[f * 64 + j], acc);
    z1[i] = fmaxf(acc, 0.f);
  }
  __syncthreads();
  float* z2 = smem;  // gg region is dead now
  for (int i = t; i < 64 * 64; i += 256) {
    int g = i >> 6, j = i & 63;
    float acc = b2[j];
    for (int f = 0; f < 64; ++f) acc = fmaf(z1[(g << 6) + f], w2[f * 64 + j], acc);
    z2[i] = fmaxf(acc, 0.f);
  }
  __syncthreads();
  if (t < 64) {
    float acc = b3[0];
    for (int j = 0; j < 64; ++j) acc = fmaf(z2[(t << 6) + j], w3[j], acc);
    out[t] = acc;
  }
}

// ---------------- launch ----------------

extern "C" void kernel_launch(void* const* d_in, const int* in_sizes, int n_in,
                              void* d_out, int out_size, void* d_ws, size_t ws_size,
                              hipStream_t stream) {
  const float* x      = (const float*)d_in[0];
  const int*   eidx   = (const int*)d_in[1];
  const int*   batch  = (const int*)d_in[2];
  const float* W_in   = (const float*)d_in[3];
  const float* b_in   = (const float*)d_in[4];
  const float* W_hid  = (const float*)d_in[5];
  const float* b_hid  = (const float*)d_in[6];
  const float* lin1_w = (const float*)d_in[7];
  const float* lin1_b = (const float*)d_in[8];
  const float* lin2_w = (const float*)d_in[9];
  const float* lin2_b = (const float*)d_in[10];
  const float* lin3_w = (const float*)d_in[11];
  const float* lin3_b = (const float*)d_in[12];
  float* out = (float*)d_out;

  const int N = in_sizes[2];            // 80000
  const int E = in_sizes[1] / 2;        // 1280000
  const int CIN = in_sizes[0] / N;      // 128
  const int n_hid = in_sizes[5] / (64 * 64);  // 5

  const int* src = eidx;
  const int* dst = eidx + E;

  // workspace layout (256B-aligned slabs)
  char* ws = (char*)d_ws;
  size_t off = 0;
  auto alloc = [&](size_t bytes) {
    size_t o = off;
    off = (off + bytes + 255) & ~(size_t)255;
    return o;
  };
  int*            deg     = (int*)(ws + alloc((size_t)N * 4));
  int*            cursor  = (int*)(ws + alloc((size_t)N * 4));
  float*          dinv    = (float*)(ws + alloc((size_t)N * 4));
  int*            offs    = (int*)(ws + alloc((size_t)N * 4));
  int*            bsums   = (int*)(ws + alloc(1024 * 4));
  int*            csr_src = (int*)(ws + alloc((size_t)E * 4));
  unsigned short* tg_a    = (unsigned short*)(ws + alloc((size_t)N * 64 * 2));
  unsigned short* tg_b    = (unsigned short*)(ws + alloc((size_t)N * 64 * 2));
  float*          hbuf    = (float*)(ws + alloc((size_t)N * 64 * 4));
  unsigned short* wf0h    = (unsigned short*)(ws + alloc(16 * 64 * 8 * 2));
  unsigned short* wf0l    = (unsigned short*)(ws + alloc(16 * 64 * 8 * 2));
  unsigned short* wfhh    = (unsigned short*)(ws + alloc(5 * 8 * 64 * 8 * 2));
  unsigned short* wfhl    = (unsigned short*)(ws + alloc(5 * 8 * 64 * 8 * 2));
  float*          gsum    = (float*)(ws + alloc(64 * 64 * 4));
  float*          gmax    = (float*)(ws + alloc(64 * 64 * 4));
  (void)ws_size; (void)n_in; (void)out_size; (void)CIN;

  const int nbN = (N + 255) / 256;   // 313

  init_kernel<<<nbN, 256, 0, stream>>>(deg, cursor, gsum, (unsigned int*)gmax, N);
  hist_kernel<<<1024, 256, 0, stream>>>(dst, deg, E, N);
  dinv_kernel<<<nbN, 256, 0, stream>>>(deg, dinv, N);
  scan1_kernel<<<nbN, 256, 0, stream>>>(deg, offs, bsums, N);
  scan2_kernel<<<1, 512, 0, stream>>>(bsums, nbN);
  scan3_kernel<<<nbN, 256, 0, stream>>>(offs, bsums, N);
  fill_kernel<<<1024, 256, 0, stream>>>(src, dst, offs, cursor, csr_src, E, N);
  wprep_kernel<<<1, 256, 0, stream>>>(W_in, W_hid, wf0h, wf0l, wfhh, wfhl);

  const int agg_blocks = (N * 64 + 255) / 256;   // one wave per node
  const int ntile = N >> 4;                      // 5000
  const int xf0_blocks = (ntile * 2 + 3) / 4;    // 2 waves per tile
  const int xf_blocks = (ntile + 3) / 4;         // 1 wave per tile

  // layer 0 transform: t'_0 = dinv * bf16(x @ W_in)
  xform0_kernel<<<xf0_blocks, 256, 0, stream>>>(x, wf0h, wf0l, dinv, tg_a, N);

  // hidden layers: agg (gather+relu, f32 h) -> split-bf16 MFMA transform
  unsigned short* cur = tg_a;
  unsigned short* nxt = tg_b;
  for (int k = 0; k < n_hid; ++k) {   // 5 layers
    const float* bias_k = (k == 0) ? b_in : (b_hid + (size_t)(k - 1) * 64);
    agg_mid_kernel<<<agg_blocks, 256, 0, stream>>>(
        cur, csr_src, offs, deg, dinv, bias_k, hbuf, N);
    xform_kernel<<<xf_blocks, 256, 0, stream>>>(
        hbuf, wfhh + (size_t)k * 8 * 64 * 8, wfhl + (size_t)k * 8 * 64 * 8,
        dinv, nxt, N);
    unsigned short* t = cur; cur = nxt; nxt = t;
  }
  // last conv: gather t'_5, bias b_hid[4], NO relu, f32 h for pooling
  agg_last_kernel<<<agg_blocks, 256, 0, stream>>>(
      cur, csr_src, offs, deg, dinv, b_hid + (size_t)(n_hid - 1) * 64, hbuf, N);

  const int pool_waves = (N + POOL_CHUNK - 1) / POOL_CHUNK;
  const int pool_blocks = (pool_waves * 64 + 255) / 256;
  pool_kernel<<<pool_blocks, 256, 0, stream>>>(hbuf, batch, gsum, gmax, N);

  mlp_kernel<<<1, 256, 0, stream>>>(gsum, gmax, lin1_w, lin1_b, lin2_w, lin2_b,
                                    lin3_w, lin3_b, out);
}

// Round 9
// 665.676 us; speedup vs baseline: 1.4584x; 1.0365x over previous
//
#include <hip/hip_runtime.h>
#include <hip/hip_bf16.h>
#include <cstdint>
#include <cstddef>

// GCN: 6 layers (128->64, then 5x 64->64), gcn_norm with self-loops,
// sum+max pooling over 64 graphs, 3-layer MLP head.
// Norm factored: h[v] = relu(b + dinv[v]*(t'[v] + sum_e t'[src_e])),
//   t'[r] = dinv[r]*(h_prev[r]@W)  stored bf16 (128B gather rows).
// Transforms: split-bf16 (hi+lo) MFMA GEMMs (~f32 accurate).
// CSR: XCD-sliced build, segments 8-PADDED with a zero-row sentinel so the
// agg gather loop is a uniform batch-of-8 (no tail, vector NT index loads).
// Streaming reads use nontemporal loads to keep L2 for hot data.

#define FEAT 64

typedef __bf16 bf16_t;
typedef bf16_t bf16x8 __attribute__((ext_vector_type(8)));
typedef float f32x4 __attribute__((ext_vector_type(4)));
typedef int intx4 __attribute__((ext_vector_type(4)));   // clang vector: OK for NT builtins

static __device__ inline unsigned short f2bf(float f) {
  unsigned u = __float_as_uint(f);
  unsigned r = (u + 0x7FFF + ((u >> 16) & 1)) >> 16;  // round-to-nearest-even
  return (unsigned short)r;
}
static __device__ inline float bf2f(unsigned short u) {
  return __uint_as_float(((unsigned)u) << 16);
}

// ---------------- setup kernels ----------------

__global__ __launch_bounds__(256) void init_kernel(int* deg, int* cursor,
    float* gsum, unsigned int* gmax, int n) {
  int i = blockIdx.x * 256 + threadIdx.x;
  if (i < n) { deg[i] = 0; cursor[i] = 0; }
  if (i < 64 * FEAT) { gsum[i] = 0.f; gmax[i] = 0xFF800000u; }  // -inf bits
}

// pad CSR with sentinel index n (zero row) + zero the sentinel rows of tg_a/b
__global__ __launch_bounds__(256) void pad_kernel(int* __restrict__ csr,
    int e8_4, int nval, unsigned short* __restrict__ tga,
    unsigned short* __restrict__ tgb, int n) {
  int i = blockIdx.x * 256 + threadIdx.x;
  if (i < e8_4) {
    intx4 v4 = {nval, nval, nval, nval};
    ((intx4*)csr)[i] = v4;
  }
  if (blockIdx.x == 0 && threadIdx.x < 64) {
    tga[(size_t)n * 64 + threadIdx.x] = 0;
    tgb[(size_t)n * 64 + threadIdx.x] = 0;
  }
}

// XCD-sliced histogram: slice s = blockIdx%8 owns dst in [s*n/8,(s+1)*n/8).
__global__ __launch_bounds__(256) void hist_kernel(const int* __restrict__ dst,
    int* __restrict__ deg, int e, int n) {
  const int slice = blockIdx.x & 7;
  const int lo = slice * (n >> 3);
  const int hi = lo + (n >> 3);
  const int nb = gridDim.x >> 3;
  const int bid = blockIdx.x >> 3;
  for (int i = bid * 256 + threadIdx.x; i < e; i += nb * 256) {
    int d = __builtin_nontemporal_load(&dst[i]);
    if (d >= lo && d < hi) atomicAdd(&deg[d], 1);
  }
}

__global__ __launch_bounds__(256) void dinv_kernel(const int* __restrict__ deg,
    float* __restrict__ dinv, int n) {
  int i = blockIdx.x * 256 + threadIdx.x;
  if (i < n) dinv[i] = rsqrtf((float)(deg[i] + 1));  // +1 self-loop; always >=1
}

// scan over 8-PADDED degrees: offs = exclusive prefix of ceil8(deg)
__global__ __launch_bounds__(256) void scan1_kernel(const int* __restrict__ deg,
    int* __restrict__ offs, int* __restrict__ bsums, int n) {
  __shared__ int buf[256];
  int t = threadIdx.x;
  int i = blockIdx.x * 256 + t;
  int v = (i < n) ? ((deg[i] + 7) & ~7) : 0;
  buf[t] = v;
  __syncthreads();
  for (int off = 1; off < 256; off <<= 1) {
    int add = (t >= off) ? buf[t - off] : 0;
    __syncthreads();
    buf[t] += add;
    __syncthreads();
  }
  if (i < n) offs[i] = buf[t] - v;           // exclusive within block
  if (t == 255) bsums[blockIdx.x] = buf[255];
}

__global__ __launch_bounds__(512) void scan2_kernel(int* bs, int nb) {
  __shared__ int buf[512];
  int t = threadIdx.x;
  int v = (t < nb) ? bs[t] : 0;
  buf[t] = v;
  __syncthreads();
  for (int off = 1; off < 512; off <<= 1) {
    int add = (t >= off) ? buf[t - off] : 0;
    __syncthreads();
    buf[t] += add;
    __syncthreads();
  }
  if (t < nb) bs[t] = buf[t] - v;            // exclusive block offsets
}

__global__ __launch_bounds__(256) void scan3_kernel(int* __restrict__ offs,
    const int* __restrict__ bs, int n) {
  int i = blockIdx.x * 256 + threadIdx.x;
  if (i < n) offs[i] += bs[blockIdx.x];
}

// XCD-sliced CSR fill: slice's cursor + CSR region stay L2-local; NT loads
// keep the edge streams from evicting the dirty CSR lines.
__global__ __launch_bounds__(256) void fill_kernel(const int* __restrict__ src,
    const int* __restrict__ dst, const int* __restrict__ offs,
    int* __restrict__ cursor, int* __restrict__ csr_src, int e, int n) {
  const int slice = blockIdx.x & 7;
  const int lo = slice * (n >> 3);
  const int hi = lo + (n >> 3);
  const int nb = gridDim.x >> 3;
  const int bid = blockIdx.x >> 3;
  for (int i = bid * 256 + threadIdx.x; i < e; i += nb * 256) {
    int d = __builtin_nontemporal_load(&dst[i]);
    if (d >= lo && d < hi) {
      int s = __builtin_nontemporal_load(&src[i]);
      int pos = offs[d] + atomicAdd(&cursor[d], 1);
      csr_src[pos] = s;
    }
  }
}

// ---------------- W fragment prep: hi/lo split bf16 ----------------
// B-frag for mfma_f32_16x16x32_bf16: lane holds B[q*32+(lane>>4)*8+j][t*16+(lane&15)]
__global__ __launch_bounds__(256) void wprep_kernel(
    const float* __restrict__ W_in, const float* __restrict__ W_hid,
    unsigned short* __restrict__ wf0h, unsigned short* __restrict__ wf0l,
    unsigned short* __restrict__ wfhh, unsigned short* __restrict__ wfhl) {
  int tid = threadIdx.x;
  for (int i = tid; i < 16 * 64 * 8; i += 256) {      // 8192
    int j = i & 7, l = (i >> 3) & 63, f = i >> 9;
    int q = f & 3, t = f >> 2;
    int k = q * 32 + (l >> 4) * 8 + j, c = t * 16 + (l & 15);
    float w = W_in[k * 64 + c];
    unsigned short hi = f2bf(w);
    wf0h[i] = hi;
    wf0l[i] = f2bf(w - bf2f(hi));
  }
  for (int i = tid; i < 5 * 8 * 64 * 8; i += 256) {   // 20480
    int j = i & 7, l = (i >> 3) & 63, f = (i >> 9) & 7, m = i >> 12;
    int q = f & 1, t = f >> 1;
    int k = q * 32 + (l >> 4) * 8 + j, c = t * 16 + (l & 15);
    float w = W_hid[(m * 64 + k) * 64 + c];
    unsigned short hi = f2bf(w);
    wfhh[i] = hi;
    wfhl[i] = f2bf(w - bf2f(hi));
  }
}

// split 8 f32 into hi/lo bf16x8 fragments
static __device__ inline void split8(const float4& a, const float4& b,
                                     bf16x8& vh, bf16x8& vl) {
  union { unsigned short us[8]; bf16x8 v; } uh, ul;
  float va[8] = {a.x, a.y, a.z, a.w, b.x, b.y, b.z, b.w};
#pragma unroll
  for (int j = 0; j < 8; ++j) {
    unsigned short hi = f2bf(va[j]);
    uh.us[j] = hi;
    ul.us[j] = f2bf(va[j] - bf2f(hi));
  }
  vh = uh.v; vl = ul.v;
}

// ---------------- layer-0 transform: tg = dinv * (x[N,128] @ W_in) ------
// 2 waves per 16-row tile (each does 2 of 4 col-tiles) to bound VGPRs.
__global__ __launch_bounds__(256) void xform0_kernel(
    const float* __restrict__ x, const unsigned short* __restrict__ wf0h,
    const unsigned short* __restrict__ wf0l, const float* __restrict__ dinv,
    unsigned short* __restrict__ tg, int n) {
  const int lane = threadIdx.x & 63;
  const int r = lane & 15, g = lane >> 4;
  const int gw = (blockIdx.x * 256 + threadIdx.x) >> 6;
  const int th = gw & 1;          // t = th*2 + tt, tt<2
  const int tile = gw >> 1;
  if (tile >= (n >> 4)) return;

  bf16x8 wh[2][4], wl[2][4];
#pragma unroll
  for (int tt = 0; tt < 2; ++tt)
#pragma unroll
    for (int q = 0; q < 4; ++q) {
      int f = (th * 2 + tt) * 4 + q;
      wh[tt][q] = *reinterpret_cast<const bf16x8*>(&wf0h[(f * 64 + lane) * 8]);
      wl[tt][q] = *reinterpret_cast<const bf16x8*>(&wf0l[(f * 64 + lane) * 8]);
    }

  const int m0 = tile << 4;
  const float* xrow = x + (size_t)(m0 + r) * 128 + g * 8;
  f32x4 acc[2] = {{0.f, 0.f, 0.f, 0.f}, {0.f, 0.f, 0.f, 0.f}};
#pragma unroll
  for (int q = 0; q < 4; ++q) {
    float4 lo4 = *(const float4*)(xrow + q * 32);
    float4 hi4 = *(const float4*)(xrow + q * 32 + 4);
    bf16x8 ah, al;
    split8(lo4, hi4, ah, al);
#pragma unroll
    for (int tt = 0; tt < 2; ++tt) {
      acc[tt] = __builtin_amdgcn_mfma_f32_16x16x32_bf16(ah, wh[tt][q], acc[tt], 0, 0, 0);
      acc[tt] = __builtin_amdgcn_mfma_f32_16x16x32_bf16(al, wh[tt][q], acc[tt], 0, 0, 0);
      acc[tt] = __builtin_amdgcn_mfma_f32_16x16x32_bf16(ah, wl[tt][q], acc[tt], 0, 0, 0);
    }
  }
  float4 dv = *(const float4*)&dinv[m0 + g * 4];
  unsigned short* orow = tg + (size_t)m0 * 64;
#pragma unroll
  for (int tt = 0; tt < 2; ++tt) {
    int c = (th * 2 + tt) * 16 + r;
    orow[(g * 4 + 0) * 64 + c] = f2bf(acc[tt][0] * dv.x);
    orow[(g * 4 + 1) * 64 + c] = f2bf(acc[tt][1] * dv.y);
    orow[(g * 4 + 2) * 64 + c] = f2bf(acc[tt][2] * dv.z);
    orow[(g * 4 + 3) * 64 + c] = f2bf(acc[tt][3] * dv.w);
  }
}

// ---------------- hidden transform: tg = dinv * (h[N,64](f32) @ W) -----
__global__ __launch_bounds__(256) void xform_kernel(
    const float* __restrict__ h, const unsigned short* __restrict__ wflh,
    const unsigned short* __restrict__ wfll, const float* __restrict__ dinv,
    unsigned short* __restrict__ tg, int n) {
  const int lane = threadIdx.x & 63;
  const int r = lane & 15, g = lane >> 4;
  const int tile = (blockIdx.x * 256 + threadIdx.x) >> 6;
  if (tile >= (n >> 4)) return;

  bf16x8 wh[4][2], wl[4][2];
#pragma unroll
  for (int t = 0; t < 4; ++t)
#pragma unroll
    for (int q = 0; q < 2; ++q) {
      int f = t * 2 + q;
      wh[t][q] = *reinterpret_cast<const bf16x8*>(&wflh[(f * 64 + lane) * 8]);
      wl[t][q] = *reinterpret_cast<const bf16x8*>(&wfll[(f * 64 + lane) * 8]);
    }

  const int m0 = tile << 4;
  const float* hrow = h + (size_t)(m0 + r) * 64 + g * 8;
  f32x4 acc[4] = {{0.f, 0.f, 0.f, 0.f}, {0.f, 0.f, 0.f, 0.f},
                  {0.f, 0.f, 0.f, 0.f}, {0.f, 0.f, 0.f, 0.f}};
#pragma unroll
  for (int q = 0; q < 2; ++q) {
    float4 lo4 = *(const float4*)(hrow + q * 32);
    float4 hi4 = *(const float4*)(hrow + q * 32 + 4);
    bf16x8 ah, al;
    split8(lo4, hi4, ah, al);
#pragma unroll
    for (int t = 0; t < 4; ++t) {
      acc[t] = __builtin_amdgcn_mfma_f32_16x16x32_bf16(ah, wh[t][q], acc[t], 0, 0, 0);
      acc[t] = __builtin_amdgcn_mfma_f32_16x16x32_bf16(al, wh[t][q], acc[t], 0, 0, 0);
      acc[t] = __builtin_amdgcn_mfma_f32_16x16x32_bf16(ah, wl[t][q], acc[t], 0, 0, 0);
    }
  }
  float4 dv = *(const float4*)&dinv[m0 + g * 4];
  unsigned short* orow = tg + (size_t)m0 * 64;
#pragma unroll
  for (int t = 0; t < 4; ++t) {
    orow[(g * 4 + 0) * 64 + t * 16 + r] = f2bf(acc[t][0] * dv.x);
    orow[(g * 4 + 1) * 64 + t * 16 + r] = f2bf(acc[t][1] * dv.y);
    orow[(g * 4 + 2) * 64 + t * 16 + r] = f2bf(acc[t][2] * dv.z);
    orow[(g * 4 + 3) * 64 + t * 16 + r] = f2bf(acc[t][3] * dv.w);
  }
}

// ---------------- AGG (mid): uniform batch-of-8 gather loop -------------
// Padding slots index row n (zero row) -> adds +0.0 exactly, no tail.
__global__ __launch_bounds__(256) void agg_mid_kernel(
    const unsigned short* __restrict__ tg_in, const int* __restrict__ csr_src,
    const int* __restrict__ offs, const int* __restrict__ cnt,
    const float* __restrict__ dinv, const float* __restrict__ bias,
    float* __restrict__ h_out, int n) {
  int v = (blockIdx.x * 256 + threadIdx.x) >> 6;
  int lane = threadIdx.x & 63;
  if (v >= n) return;
  float acc = bf2f(tg_in[(size_t)v * 64 + lane]);  // self term
  int j = offs[v];
  int nb = (cnt[v] + 7) >> 3;
  for (int b = 0; b < nb; ++b, j += 8) {
    intx4 ia = __builtin_nontemporal_load((const intx4*)(csr_src + j));
    intx4 ib = __builtin_nontemporal_load((const intx4*)(csr_src + j + 4));
    float t0 = bf2f(tg_in[(size_t)ia.x * 64 + lane]);
    float t1 = bf2f(tg_in[(size_t)ia.y * 64 + lane]);
    float t2 = bf2f(tg_in[(size_t)ia.z * 64 + lane]);
    float t3 = bf2f(tg_in[(size_t)ia.w * 64 + lane]);
    float t4 = bf2f(tg_in[(size_t)ib.x * 64 + lane]);
    float t5 = bf2f(tg_in[(size_t)ib.y * 64 + lane]);
    float t6 = bf2f(tg_in[(size_t)ib.z * 64 + lane]);
    float t7 = bf2f(tg_in[(size_t)ib.w * 64 + lane]);
    acc += ((t0 + t1) + (t2 + t3)) + ((t4 + t5) + (t6 + t7));
  }
  h_out[(size_t)v * 64 + lane] = fmaxf(fmaf(dinv[v], acc, bias[lane]), 0.f);
}

// ---------------- last AGG (layer 5): no relu, f32 out for pooling ------
__global__ __launch_bounds__(256) void agg_last_kernel(
    const unsigned short* __restrict__ tg_in, const int* __restrict__ csr_src,
    const int* __restrict__ offs, const int* __restrict__ cnt,
    const float* __restrict__ dinv, const float* __restrict__ bias,
    float* __restrict__ h, int n) {
  int v = (blockIdx.x * 256 + threadIdx.x) >> 6;
  int lane = threadIdx.x & 63;
  if (v >= n) return;
  float acc = bf2f(tg_in[(size_t)v * 64 + lane]);
  int j = offs[v];
  int nb = (cnt[v] + 7) >> 3;
  for (int b = 0; b < nb; ++b, j += 8) {
    intx4 ia = __builtin_nontemporal_load((const intx4*)(csr_src + j));
    intx4 ib = __builtin_nontemporal_load((const intx4*)(csr_src + j + 4));
    float t0 = bf2f(tg_in[(size_t)ia.x * 64 + lane]);
    float t1 = bf2f(tg_in[(size_t)ia.y * 64 + lane]);
    float t2 = bf2f(tg_in[(size_t)ia.z * 64 + lane]);
    float t3 = bf2f(tg_in[(size_t)ia.w * 64 + lane]);
    float t4 = bf2f(tg_in[(size_t)ib.x * 64 + lane]);
    float t5 = bf2f(tg_in[(size_t)ib.y * 64 + lane]);
    float t6 = bf2f(tg_in[(size_t)ib.z * 64 + lane]);
    float t7 = bf2f(tg_in[(size_t)ib.w * 64 + lane]);
    acc += ((t0 + t1) + (t2 + t3)) + ((t4 + t5) + (t6 + t7));
  }
  h[(size_t)v * 64 + lane] = fmaf(dinv[v], acc, bias[lane]);  // no relu
}

// ---------------- pooling: per-graph sum + max ----------------

__device__ inline void atomic_max_float(float* addr, float val) {
  if (val >= 0.f)
    atomicMax((int*)addr, __float_as_int(val));
  else
    atomicMin((unsigned int*)addr, (unsigned int)__float_as_int(val));
}

#define POOL_CHUNK 128

__global__ __launch_bounds__(256) void pool_kernel(const float* __restrict__ h,
    const int* __restrict__ batch, float* __restrict__ gsum,
    float* __restrict__ gmax, int n) {
  int wave = (blockIdx.x * 256 + threadIdx.x) >> 6;
  int lane = threadIdx.x & 63;
  int start = wave * POOL_CHUNK;
  if (start >= n) return;
  int end = min(start + POOL_CHUNK, n);
  float s = 0.f, m = -INFINITY;
  int cur = batch[start];
  for (int v = start; v < end; ++v) {
    int g = batch[v];
    if (g != cur) {
      atomicAdd(&gsum[cur * 64 + lane], s);
      atomic_max_float(&gmax[cur * 64 + lane], m);
      s = 0.f; m = -INFINITY; cur = g;
    }
    float x = h[(size_t)v * 64 + lane];
    s += x;
    m = fmaxf(m, x);
  }
  atomicAdd(&gsum[cur * 64 + lane], s);
  atomic_max_float(&gmax[cur * 64 + lane], m);
}

// ---------------- MLP head (single block) ----------------

__global__ __launch_bounds__(256) void mlp_kernel(const float* __restrict__ gsum,
    const float* __restrict__ gmax, const float* __restrict__ w1,
    const float* __restrict__ b1, const float* __restrict__ w2,
    const float* __restrict__ b2, const float* __restrict__ w3,
    const float* __restrict__ b3, float* __restrict__ out) {
  __shared__ float smem[64 * 128 + 64 * 64];  // 48KB: gg then z1; z2 overlays gg
  float* gg = smem;
  float* z1 = smem + 64 * 128;
  int t = threadIdx.x;
  for (int i = t; i < 64 * 128; i += 256) {
    int g = i >> 7, f = i & 127;
    gg[i] = (f < 64) ? gsum[g * 64 + f] : gmax[g * 64 + (f - 64)];
  }
  __syncthreads();
  for (int i = t; i < 64 * 64; i += 256) {
    int g = i >> 6, j = i & 63;
    float acc = b1[j];
    for (int f = 0; f < 128; ++f) acc = fmaf(gg[(g << 7) + f], w1[f * 64 + j], acc);
    z1[i] = fmaxf(acc, 0.f);
  }
  __syncthreads();
  float* z2 = smem;  // gg region is dead now
  for (int i = t; i < 64 * 64; i += 256) {
    int g = i >> 6, j = i & 63;
    float acc = b2[j];
    for (int f = 0; f < 64; ++f) acc = fmaf(z1[(g << 6) + f], w2[f * 64 + j], acc);
    z2[i] = fmaxf(acc, 0.f);
  }
  __syncthreads();
  if (t < 64) {
    float acc = b3[0];
    for (int j = 0; j < 64; ++j) acc = fmaf(z2[(t << 6) + j], w3[j], acc);
    out[t] = acc;
  }
}

// ---------------- launch ----------------

extern "C" void kernel_launch(void* const* d_in, const int* in_sizes, int n_in,
                              void* d_out, int out_size, void* d_ws, size_t ws_size,
                              hipStream_t stream) {
  const float* x      = (const float*)d_in[0];
  const int*   eidx   = (const int*)d_in[1];
  const int*   batch  = (const int*)d_in[2];
  const float* W_in   = (const float*)d_in[3];
  const float* b_in   = (const float*)d_in[4];
  const float* W_hid  = (const float*)d_in[5];
  const float* b_hid  = (const float*)d_in[6];
  const float* lin1_w = (const float*)d_in[7];
  const float* lin1_b = (const float*)d_in[8];
  const float* lin2_w = (const float*)d_in[9];
  const float* lin2_b = (const float*)d_in[10];
  const float* lin3_w = (const float*)d_in[11];
  const float* lin3_b = (const float*)d_in[12];
  float* out = (float*)d_out;

  const int N = in_sizes[2];            // 80000
  const int E = in_sizes[1] / 2;        // 1280000
  const int CIN = in_sizes[0] / N;      // 128
  const int n_hid = in_sizes[5] / (64 * 64);  // 5

  const int* src = eidx;
  const int* dst = eidx + E;

  const int E8 = E + 8 * N;             // padded CSR capacity

  // workspace layout (256B-aligned slabs)
  char* ws = (char*)d_ws;
  size_t off = 0;
  auto alloc = [&](size_t bytes) {
    size_t o = off;
    off = (off + bytes + 255) & ~(size_t)255;
    return o;
  };
  int*            deg     = (int*)(ws + alloc((size_t)N * 4));
  int*            cursor  = (int*)(ws + alloc((size_t)N * 4));
  float*          dinv    = (float*)(ws + alloc((size_t)N * 4));
  int*            offs    = (int*)(ws + alloc((size_t)N * 4));
  int*            bsums   = (int*)(ws + alloc(1024 * 4));
  int*            csr_src = (int*)(ws + alloc((size_t)E8 * 4));
  unsigned short* tg_a    = (unsigned short*)(ws + alloc((size_t)(N + 1) * 64 * 2));
  unsigned short* tg_b    = (unsigned short*)(ws + alloc((size_t)(N + 1) * 64 * 2));
  float*          hbuf    = (float*)(ws + alloc((size_t)N * 64 * 4));
  unsigned short* wf0h    = (unsigned short*)(ws + alloc(16 * 64 * 8 * 2));
  unsigned short* wf0l    = (unsigned short*)(ws + alloc(16 * 64 * 8 * 2));
  unsigned short* wfhh    = (unsigned short*)(ws + alloc(5 * 8 * 64 * 8 * 2));
  unsigned short* wfhl    = (unsigned short*)(ws + alloc(5 * 8 * 64 * 8 * 2));
  float*          gsum    = (float*)(ws + alloc(64 * 64 * 4));
  float*          gmax    = (float*)(ws + alloc(64 * 64 * 4));
  (void)ws_size; (void)n_in; (void)out_size; (void)CIN;

  const int nbN = (N + 255) / 256;   // 313
  const int e8_4 = E8 / 4;           // intx4 count (E8 % 4 == 0)

  init_kernel<<<nbN, 256, 0, stream>>>(deg, cursor, gsum, (unsigned int*)gmax, N);
  pad_kernel<<<(e8_4 + 255) / 256, 256, 0, stream>>>(csr_src, e8_4, N, tg_a, tg_b, N);
  hist_kernel<<<2048, 256, 0, stream>>>(dst, deg, E, N);
  dinv_kernel<<<nbN, 256, 0, stream>>>(deg, dinv, N);
  scan1_kernel<<<nbN, 256, 0, stream>>>(deg, offs, bsums, N);
  scan2_kernel<<<1, 512, 0, stream>>>(bsums, nbN);
  scan3_kernel<<<nbN, 256, 0, stream>>>(offs, bsums, N);
  fill_kernel<<<2048, 256, 0, stream>>>(src, dst, offs, cursor, csr_src, E, N);
  wprep_kernel<<<1, 256, 0, stream>>>(W_in, W_hid, wf0h, wf0l, wfhh, wfhl);

  const int agg_blocks = (N * 64 + 255) / 256;   // one wave per node
  const int ntile = N >> 4;                      // 5000
  const int xf0_blocks = (ntile * 2 + 3) / 4;    // 2 waves per tile
  const int xf_blocks = (ntile + 3) / 4;         // 1 wave per tile

  // layer 0 transform: t'_0 = dinv * bf16(x @ W_in)
  xform0_kernel<<<xf0_blocks, 256, 0, stream>>>(x, wf0h, wf0l, dinv, tg_a, N);

  // hidden layers: agg (gather+relu, f32 h) -> split-bf16 MFMA transform
  unsigned short* cur = tg_a;
  unsigned short* nxt = tg_b;
  for (int k = 0; k < n_hid; ++k) {   // 5 layers
    const float* bias_k = (k == 0) ? b_in : (b_hid + (size_t)(k - 1) * 64);
    agg_mid_kernel<<<agg_blocks, 256, 0, stream>>>(
        cur, csr_src, offs, deg, dinv, bias_k, hbuf, N);
    xform_kernel<<<xf_blocks, 256, 0, stream>>>(
        hbuf, wfhh + (size_t)k * 8 * 64 * 8, wfhl + (size_t)k * 8 * 64 * 8,
        dinv, nxt, N);
    unsigned short* t = cur; cur = nxt; nxt = t;
  }
  // last conv: gather t'_5, bias b_hid[4], NO relu, f32 h for pooling
  agg_last_kernel<<<agg_blocks, 256, 0, stream>>>(
      cur, csr_src, offs, deg, dinv, b_hid + (size_t)(n_hid - 1) * 64, hbuf, N);

  const int pool_waves = (N + POOL_CHUNK - 1) / POOL_CHUNK;
  const int pool_blocks = (pool_waves * 64 + 255) / 256;
  pool_kernel<<<pool_blocks, 256, 0, stream>>>(hbuf, batch, gsum, gmax, N);

  mlp_kernel<<<1, 256, 0, stream>>>(gsum, gmax, lin1_w, lin1_b, lin2_w, lin2_b,
                                    lin3_w, lin3_b, out);
}